// Round 4
// baseline (2235.368 us; speedup 1.0000x reference)
//
#include <hip/hip_runtime.h>
#include <stdint.h>

#define M_DIM 8192
#define N_DIM 11008
#define K_DIM 4096
#define KP    2048      // K/2 int32 per packed-W row
#define NG    32        // scale groups per row (K/128)
#define BM    128
#define BN    128
#define BK    32
#define KSTEPS (K_DIM / BK)   // 128

typedef __attribute__((ext_vector_type(8))) _Float16 half8;   // MFMA A/B frag (4 VGPRs)
typedef __attribute__((ext_vector_type(4))) float    floatx4; // MFMA C/D frag
typedef __attribute__((ext_vector_type(4))) int      intx4;

__global__ __launch_bounds__(256, 2)
void w4a16_gemm(const float* __restrict__ X,       // fp16 values delivered as fp32
                const int* __restrict__ Wp,        // [N, K/2] one byte per int32
                const float* __restrict__ Sc,      // fp16 scales delivered as fp32
                float* __restrict__ Out)           // fp16 output delivered as fp32
{
    __shared__ __align__(16) _Float16 Alds[BM * BK];   // 8 KB
    __shared__ __align__(16) _Float16 Blds[BN * BK];   // 8 KB

    const int tid = threadIdx.x;
    const int bn  = blockIdx.x;   // 0..85
    const int bm  = blockIdx.y;   // 0..63

    // staging mapping (shared by A and B): row = tid>>1 (0..127), half = tid&1
    const int srow  = tid >> 1;
    const int shalf = tid & 1;

    // ---- A: thread loads 16 fp32 (4x float4), converts to 16 fp16, 32B -> LDS
    const float* Ag = X + (size_t)(bm * BM + srow) * K_DIM + shalf * 16;
    _Float16* Al = Alds + srow * BK + shalf * 16;

    // ---- B: thread loads 8 int32 (2x int4) = 16 k-values, dequant fp16 -> LDS
    const int gn = bn * BN + srow;
    const int* Bg = Wp + (size_t)gn * KP + shalf * 8;
    const float* Srow = Sc + (size_t)gn * NG;
    _Float16* Bl = Blds + srow * BK + shalf * 16;

    // ---- MFMA fragment addressing (16x16x32, m89/m91-verified mapping)
    const int lane = tid & 63;
    const int wave = tid >> 6;
    const int wm   = (wave >> 1) * 64;
    const int wn   = (wave & 1) * 64;
    const int l16  = lane & 15;
    const int quad = lane >> 4;

    const _Float16* Ar = Alds + (wm + l16) * BK + quad * 8;
    const _Float16* Br = Blds + (wn + l16) * BK + quad * 8;

    floatx4 acc[4][4];
#pragma unroll
    for (int i = 0; i < 4; ++i)
#pragma unroll
        for (int j = 0; j < 4; ++j)
            acc[i][j] = (floatx4){0.f, 0.f, 0.f, 0.f};

    // prologue: prefetch step-0 A (fp32) and packed B into registers
    floatx4 ax[4];
#pragma unroll
    for (int i = 0; i < 4; ++i) ax[i] = *(const floatx4*)(Ag + i * 4);
    intx4 bp0 = *(const intx4*)Bg;
    intx4 bp1 = *(const intx4*)(Bg + 4);
    float sc  = Srow[0];

    for (int ks = 0; ks < KSTEPS; ++ks) {
        __syncthreads();   // previous iteration's LDS reads complete

        // A: fp32 -> fp16 (exact: values originated as fp16)
        _Float16 ab[16];
#pragma unroll
        for (int i = 0; i < 4; ++i) {
#pragma unroll
            for (int j = 0; j < 4; ++j)
                ab[4 * i + j] = (_Float16)ax[i][j];
        }
        ((intx4*)Al)[0] = ((const intx4*)ab)[0];
        ((intx4*)Al)[1] = ((const intx4*)ab)[1];

        // B: dequant (q - 8) * sc in fp32 (exact product), RN to fp16
        const float s8 = sc * 8.0f;
        _Float16 wb[16];
#pragma unroll
        for (int i = 0; i < 4; ++i) {
            unsigned p = (unsigned)bp0[i];
            wb[2 * i + 0] = (_Float16)fmaf((float)(p & 0xFu), sc, -s8);
            wb[2 * i + 1] = (_Float16)fmaf((float)((p >> 4) & 0xFu), sc, -s8);
        }
#pragma unroll
        for (int i = 0; i < 4; ++i) {
            unsigned p = (unsigned)bp1[i];
            wb[8 + 2 * i + 0] = (_Float16)fmaf((float)(p & 0xFu), sc, -s8);
            wb[8 + 2 * i + 1] = (_Float16)fmaf((float)((p >> 4) & 0xFu), sc, -s8);
        }
        ((intx4*)Bl)[0] = ((const intx4*)wb)[0];
        ((intx4*)Bl)[1] = ((const intx4*)wb)[1];

        // prefetch next step into registers (uniform branch)
        if (ks + 1 < KSTEPS) {
            const float* Agn = Ag + (ks + 1) * BK;
#pragma unroll
            for (int i = 0; i < 4; ++i) ax[i] = *(const floatx4*)(Agn + i * 4);
            const int* Bgn = Bg + (ks + 1) * (BK / 2);
            bp0 = *(const intx4*)Bgn;
            bp1 = *(const intx4*)(Bgn + 4);
            sc  = Srow[(ks + 1) >> 2];
        }

        __syncthreads();   // A and B tiles visible to all waves

        half8 af[4], bfr[4];
#pragma unroll
        for (int i = 0; i < 4; ++i) {
            af[i]  = *(const half8*)(Ar + i * 16 * BK);
            bfr[i] = *(const half8*)(Br + i * 16 * BK);
        }
#pragma unroll
        for (int mi = 0; mi < 4; ++mi)
#pragma unroll
            for (int ni = 0; ni < 4; ++ni)
                acc[mi][ni] = __builtin_amdgcn_mfma_f32_16x16x32_f16(
                    af[mi], bfr[ni], acc[mi][ni], 0, 0, 0);
    }

    // epilogue: C/D layout col(n) = lane&15, row(m) = quad*4 + reg; fp32 out
    const int row0 = bm * BM + wm + quad * 4;
    const int col0 = bn * BN + wn + l16;
#pragma unroll
    for (int mi = 0; mi < 4; ++mi) {
#pragma unroll
        for (int r = 0; r < 4; ++r) {
            const size_t row = (size_t)(row0 + mi * 16 + r);
            float* orow = Out + row * N_DIM + col0;
#pragma unroll
            for (int ni = 0; ni < 4; ++ni)
                orow[ni * 16] = acc[mi][ni][r];
        }
    }
}

extern "C" void kernel_launch(void* const* d_in, const int* in_sizes, int n_in,
                              void* d_out, int out_size, void* d_ws, size_t ws_size,
                              hipStream_t stream) {
    const float* X  = (const float*)d_in[0];
    const int*   Wp = (const int*)d_in[1];
    const float* Sc = (const float*)d_in[2];
    float*       Out = (float*)d_out;

    dim3 grid(N_DIM / BN, M_DIM / BM);   // 86 x 64
    w4a16_gemm<<<grid, dim3(256), 0, stream>>>(X, Wp, Sc, Out);
}